// Round 4
// baseline (135.809 us; speedup 1.0000x reference)
//
#include <hip/hip_runtime.h>

#define NN 50000
#define NE 100000
#define IN_F 63
#define HID 64
#define NREL 8
#define CHUNK 64

// ---------------- degree kernel: float histograms of senders/receivers ----
__global__ __launch_bounds__(256) void deg_kernel(const int* __restrict__ senders,
                                                  const int* __restrict__ receivers,
                                                  float* __restrict__ sdeg,
                                                  float* __restrict__ rdeg) {
    int e = blockIdx.x * 256 + threadIdx.x;
    if (e < NE) {
        atomicAdd(&sdeg[senders[e]], 1.0f);
        atomicAdd(&rdeg[receivers[e]], 1.0f);
    }
}

// ---------------- edge kernel ----------------
// Wave = (chunk of 64 edges, relation t). Lane f keeps K[t][0..62][f] PINNED
// in 63 VGPRs (asm "+v" prevents spill/rematerialized reloads — round-1
// showed VGPR_Count=52 < 63, i.e. the K column was being re-read per edge).
// Lanes cooperatively preload packed edge metadata; ballot picks matching
// edges; the serial loop handles TWO edges/iter with 4 rotating accumulators
// each (8 indep FMA chains) and one coalesced 256B atomicAdd per edge.
__global__ __launch_bounds__(256, 4) void edge_kernel(const float* __restrict__ nodes,
                                                      const int* __restrict__ senders,
                                                      const int* __restrict__ receivers,
                                                      const int* __restrict__ etypes,
                                                      const float* __restrict__ kernels,
                                                      const float* __restrict__ sdeg,
                                                      float* __restrict__ agg) {
    const int lane = threadIdx.x & 63;
    const int t = blockIdx.x & (NREL - 1);
    const int chunk = (blockIdx.x >> 3) * 4 + (threadIdx.x >> 6);
    const int base = chunk * CHUNK;
    if (base >= NE) return;
    const int lim = min(base + CHUNK, NE);

    // this wave's relation column: load once, pin in VGPRs
    float kcol[IN_F];
    const float* Kt = kernels + (size_t)t * IN_F * HID;
#pragma unroll
    for (int i = 0; i < IN_F; ++i) kcol[i] = Kt[i * HID + lane];
#pragma unroll
    for (int i = 0; i < IN_F; ++i) asm volatile("" : "+v"(kcol[i]));

    // cooperative preload of edge metadata (s,r packed: both < 2^16)
    const int e = base + lane;
    int pack_l = 0, ty = -1;
    int s_tmp = 0;
    if (e < lim) {
        ty    = etypes[e];
        s_tmp = senders[e];
        pack_l = s_tmp | (receivers[e] << 16);
    }
    float ns_l = 1.0f;
    if (ty == t) ns_l = rsqrtf(fmaxf(sdeg[s_tmp], 1.0f));  // predicated gather

    unsigned long long m = __ballot(ty == t);
    while (m) {
        const int i0 = __builtin_ctzll(m); m &= m - 1;
        const bool has2 = (m != 0);
        const int i1 = has2 ? __builtin_ctzll(m) : i0;
        if (has2) m &= m - 1;

        const int   p0  = __builtin_amdgcn_readfirstlane(__shfl(pack_l, i0));
        const float ns0 = __shfl(ns_l, i0);
        const int   p1  = __builtin_amdgcn_readfirstlane(__shfl(pack_l, i1));
        const float ns1 = __shfl(ns_l, i1);
        const int s0 = p0 & 0xFFFF, r0 = ((unsigned)p0) >> 16;
        const int s1 = p1 & 0xFFFF, r1 = ((unsigned)p1) >> 16;

        const float4* xa = (const float4*)(nodes + (size_t)s0 * (IN_F + 1));
        const float4* xb = (const float4*)(nodes + (size_t)s1 * (IN_F + 1));
        float a0 = 0.f, a1 = 0.f, a2 = 0.f, a3 = 0.f;
        float b0 = 0.f, b1 = 0.f, b2 = 0.f, b3 = 0.f;
#pragma unroll
        for (int j = 0; j < 16; ++j) {
            const float4 va = xa[j];
            const float4 vb = xb[j];
            a0 = fmaf(kcol[4 * j + 0], va.x, a0);
            a1 = fmaf(kcol[4 * j + 1], va.y, a1);
            a2 = fmaf(kcol[4 * j + 2], va.z, a2);
            if (4 * j + 3 < IN_F) a3 = fmaf(kcol[4 * j + 3], va.w, a3);
            b0 = fmaf(kcol[4 * j + 0], vb.x, b0);
            b1 = fmaf(kcol[4 * j + 1], vb.y, b1);
            b2 = fmaf(kcol[4 * j + 2], vb.z, b2);
            if (4 * j + 3 < IN_F) b3 = fmaf(kcol[4 * j + 3], vb.w, b3);
        }
        atomicAdd(&agg[(size_t)r0 * HID + lane], ((a0 + a1) + (a2 + a3)) * ns0);
        if (has2)
            atomicAdd(&agg[(size_t)r1 * HID + lane], ((b0 + b1) + (b2 + b3)) * ns1);
    }
}

// ---------------- readout: sum_n is_root[n] * relu(agg[n]*nr[n]) . w + b ---
__global__ __launch_bounds__(256) void readout_kernel(const float* __restrict__ nodes,
                                                      const float* __restrict__ agg,
                                                      const float* __restrict__ rdeg,
                                                      const float* __restrict__ w,
                                                      const float* __restrict__ b,
                                                      float* __restrict__ out) {
    __shared__ float bsum;
    if (threadIdx.x == 0) bsum = 0.f;
    __syncthreads();

    const int lane = threadIdx.x & 63;
    const int gw = blockIdx.x * 4 + (threadIdx.x >> 6);
    const int nw = gridDim.x * 4;
    const float wf = w[lane];

    float local = 0.f;  // lane f accumulates sum_n is_root[n]*relu(agg[n,f]*nr[n])
    for (int n = gw; n < NN; n += nw) {
        float a = agg[(size_t)n * HID + lane];
        float nr = rsqrtf(fmaxf(rdeg[n], 1.0f));
        float root = nodes[(size_t)n * (IN_F + 1) + IN_F];  // wave-uniform
        local += fmaxf(a * nr, 0.f) * root;
    }
    float v = local * wf;
#pragma unroll
    for (int o = 32; o > 0; o >>= 1) v += __shfl_xor(v, o, 64);

    if (lane == 0) atomicAdd(&bsum, v);
    __syncthreads();
    if (threadIdx.x == 0) {
        float val = bsum;
        if (blockIdx.x == 0) val += b[0];
        atomicAdd(out, val);
    }
}

extern "C" void kernel_launch(void* const* d_in, const int* in_sizes, int n_in,
                              void* d_out, int out_size, void* d_ws, size_t ws_size,
                              hipStream_t stream) {
    const float* nodes     = (const float*)d_in[0];
    const int*   senders   = (const int*)d_in[1];
    const int*   receivers = (const int*)d_in[2];
    const int*   etypes    = (const int*)d_in[3];
    // d_in[4] = n_node (single graph; unused)
    const float* kernels   = (const float*)d_in[5];
    const float* dense_w   = (const float*)d_in[6];
    const float* dense_b   = (const float*)d_in[7];
    float* out = (float*)d_out;

    float* agg  = (float*)d_ws;                 // NN x HID
    float* sdeg = agg + (size_t)NN * HID;       // NN
    float* rdeg = sdeg + NN;                    // NN

    size_t zero_bytes = ((size_t)NN * HID + 2 * (size_t)NN) * sizeof(float);
    hipMemsetAsync(d_ws, 0, zero_bytes, stream);
    hipMemsetAsync(d_out, 0, sizeof(float), stream);

    deg_kernel<<<(NE + 255) / 256, 256, 0, stream>>>(senders, receivers, sdeg, rdeg);

    const int nchunks = (NE + CHUNK - 1) / CHUNK;          // 1563
    const int cgroups = (nchunks + 3) / 4;                 // 391
    const int blocks  = cgroups * NREL;                    // 3128
    edge_kernel<<<blocks, 256, 0, stream>>>(nodes, senders, receivers, etypes,
                                            kernels, sdeg, agg);

    readout_kernel<<<1024, 256, 0, stream>>>(nodes, agg, rdeg, dense_w, dense_b, out);
}